// Round 6
// baseline (1278.021 us; speedup 1.0000x reference)
//
#include <hip/hip_runtime.h>
#include <hip/hip_cooperative_groups.h>

namespace cg = cooperative_groups;

// 2-layer GCN in ONE cooperative kernel (6 phases, grid.sync between):
//   P0: zero deg/state | x -> bf16 | W1 -> bf16 B-fragment pack | b1/W2 pad
//   P1: deg histogram (in-degree)
//   P2: decoupled-lookback exclusive scan -> row_ptr, cursor(seed), dinv  (blocks<196)
//   P3: CSR fill (atomic cursor bump)
//   P4: per 16-node tile: gather A = D^-1/2 (A+I) D^-1/2 X (bf16->LDS),
//       zd = dinv * ( relu(A@W1 + b1) @ W2 ) via mfma_f32_16x16x32_bf16
//   P5: out[i] = dinv[i]*(sum_{s in N(i)} zd[s] + zd[i]) + b2

#define N_NODES 50000
#define N_EDGES 800000
#define D_FEAT  128
#define D_HID   500
#define SCANB   196          // ceil(50000/256)
#define NTILES  3125         // 50000 / 16

typedef __bf16 bf16x8 __attribute__((ext_vector_type(8)));
typedef float  f32x4  __attribute__((ext_vector_type(4)));

static __device__ inline unsigned int f2bf(float f) {   // fp32 -> bf16 bits, RTNE
    unsigned int u = __float_as_uint(f);
    return (u + 0x7fffu + ((u >> 16) & 1u)) >> 16;
}
static __device__ inline float bf_lo(unsigned int u) { return __uint_as_float(u << 16); }
static __device__ inline float bf_hi(unsigned int u) { return __uint_as_float(u & 0xffff0000u); }

static __device__ inline void acc8(float* acc, uint4 u, float w) {
    acc[0] = fmaf(w, bf_lo(u.x), acc[0]);
    acc[1] = fmaf(w, bf_hi(u.x), acc[1]);
    acc[2] = fmaf(w, bf_lo(u.y), acc[2]);
    acc[3] = fmaf(w, bf_hi(u.y), acc[3]);
    acc[4] = fmaf(w, bf_lo(u.z), acc[4]);
    acc[5] = fmaf(w, bf_hi(u.z), acc[5]);
    acc[6] = fmaf(w, bf_lo(u.w), acc[6]);
    acc[7] = fmaf(w, bf_hi(u.w), acc[7]);
}

struct Params {
    const float* x;
    const int*   src;
    const int*   dst;
    const float* W1;
    const float* b1;
    const float* W2;
    const float* b2;
    float* out;
    uint2* x_bf;
    unsigned short* b_pk;
    float* b1p;
    float* w2p;
    float* dinv;
    float* zd;
    int* deg;
    unsigned int* state;
    int* row_ptr;
    int* cursor;
    int* csr;
};

__global__ __launch_bounds__(256, 8) void k_all(Params P) {
    cg::grid_group grid = cg::this_grid();
    __shared__ int ps[256];
    __shared__ int s_prefix;
    __shared__ unsigned short A[16][136];   // bf16 rows; 272B stride, 2-way alias = free
    __shared__ float red[4][16];

    const int tid  = threadIdx.x;
    const int b    = blockIdx.x;
    const int gtid = b * 256 + tid;
    const int nthr = gridDim.x * 256;

    // ================= P0: zero + convert + pack =================
    for (int i = gtid; i < N_NODES; i += nthr) P.deg[i] = 0;
    if (gtid < 256) P.state[gtid] = 0;
    for (int i = gtid; i < N_NODES * D_FEAT / 4; i += nthr) {   // x -> bf16, 4/thread
        float4 v = ((const float4*)P.x)[i];
        uint2 o;
        o.x = f2bf(v.x) | (f2bf(v.y) << 16);
        o.y = f2bf(v.z) | (f2bf(v.w) << 16);
        P.x_bf[i] = o;
    }
    for (int idx = gtid; idx < 8192; idx += nthr) {             // W1 B-fragment pack
        int lane = idx & 63;
        int slot = idx >> 6;
        int tt   = slot >> 2;                 // n-tile
        int ks   = slot & 3;                  // k-step
        int quad = lane >> 4;
        int n    = tt * 16 + (lane & 15);
        unsigned int us[8];
#pragma unroll
        for (int j = 0; j < 8; j++) {
            int k = ks * 32 + quad * 8 + j;
            float v = (n < D_HID) ? P.W1[(size_t)k * D_HID + n] : 0.f;
            us[j] = f2bf(v);
        }
        uint4 pk;
        pk.x = us[0] | (us[1] << 16);
        pk.y = us[2] | (us[3] << 16);
        pk.z = us[4] | (us[5] << 16);
        pk.w = us[6] | (us[7] << 16);
        ((uint4*)P.b_pk)[idx] = pk;
    }
    for (int i = gtid; i < 512; i += nthr) {                    // pad b1 / W2
        P.b1p[i] = (i < D_HID) ? P.b1[i] : 0.f;
        P.w2p[i] = (i < D_HID) ? P.W2[i] : 0.f;
    }
    __threadfence();
    grid.sync();

    // ================= P1: degree histogram =================
    for (int e = gtid; e < N_EDGES; e += nthr) atomicAdd(&P.deg[P.dst[e]], 1);
    __threadfence();
    grid.sync();

    // ================= P2: decoupled-lookback scan (blocks < SCANB) =========
    if (b < SCANB) {
        const int i = b * 256 + tid;
        if (tid == 0) s_prefix = 0;
        int v = (i < N_NODES) ? P.deg[i] : 0;
        ps[tid] = v;
        __syncthreads();
        for (int off = 1; off < 256; off <<= 1) {
            int t = (tid >= off) ? ps[tid - off] : 0;
            __syncthreads();
            ps[tid] += t;
            __syncthreads();
        }
        const int total = ps[255];
        if (tid == 0) {
            unsigned int st = (b == 0) ? (0xC0000000u | (unsigned)total)
                                       : (0x40000000u | (unsigned)total);
            __hip_atomic_store(&P.state[b], st, __ATOMIC_RELEASE, __HIP_MEMORY_SCOPE_AGENT);
        }
        if (b > 0 && tid < 64) {               // wave 0: 64-wide lookback
            int prefix = 0;
            int look = b - 1;
            while (true) {
                int idx = look - tid;
                unsigned int st = 0xC0000000u; // idx<0: virtual INCL value 0
                if (idx >= 0)
                    st = __hip_atomic_load(&P.state[idx], __ATOMIC_ACQUIRE,
                                           __HIP_MEMORY_SCOPE_AGENT);
                bool ready = (st >> 30) == 1u || (st >> 30) == 3u;
                if (__ballot(!ready)) continue;
                bool incl = (st >> 30) == 3u;
                unsigned long long im = __ballot(incl);
                int contrib;
                if (im == 0ull) {
                    contrib = (int)(st & 0x3FFFFFFFu);
                } else {
                    int stop = __ffsll(im) - 1;
                    contrib = (tid <= stop) ? (int)(st & 0x3FFFFFFFu) : 0;
                }
#pragma unroll
                for (int off = 32; off >= 1; off >>= 1) contrib += __shfl_xor(contrib, off);
                prefix += contrib;
                if (im != 0ull) break;
                look -= 64;
            }
            if (tid == 0) {
                s_prefix = prefix;
                __hip_atomic_store(&P.state[b], 0xC0000000u | (unsigned)(prefix + total),
                                   __ATOMIC_RELEASE, __HIP_MEMORY_SCOPE_AGENT);
            }
        }
        __syncthreads();
        const int bp = s_prefix;
        if (i < N_NODES) {
            int r = bp + ps[tid] - v;          // exclusive prefix
            P.row_ptr[i] = r;
            P.cursor[i] = r;
            P.dinv[i] = rsqrtf((float)(v + 1));
        }
        if (b == 0 && tid == 0) P.row_ptr[N_NODES] = N_EDGES;
    }
    __threadfence();
    grid.sync();

    // ================= P3: CSR fill =================
    for (int e = gtid; e < N_EDGES; e += nthr) {
        int pos = atomicAdd(&P.cursor[P.dst[e]], 1);
        P.csr[pos] = P.src[e];
    }
    __threadfence();
    grid.sync();

    // ================= P4: fused gather + bf16 MFMA MLP =================
    const int wv = tid >> 6, lane = tid & 63;
    const int q = lane >> 4, p = lane & 15;
    const uint4* __restrict__ xb4 = (const uint4*)P.x_bf;
    const bf16x8* __restrict__ bpk = (const bf16x8*)P.b_pk;

    for (int tile = b; tile < NTILES; tile += gridDim.x) {
        const int node0 = tile * 16;
        // gather: wave handles 4 nodes; quarter-wave q owns edge e+q (16B/lane)
        for (int nn = 0; nn < 4; nn++) {
            const int n = wv * 4 + nn;
            const int node = node0 + n;
            int e = P.row_ptr[node];
            const int end = P.row_ptr[node + 1];
            float acc[8];
#pragma unroll
            for (int j = 0; j < 8; j++) acc[j] = 0.f;

            for (; e + 16 <= end; e += 16) {   // 16 edges / wave iteration
                int s0 = P.csr[e + q];
                int s1 = P.csr[e + 4 + q];
                int s2 = P.csr[e + 8 + q];
                int s3 = P.csr[e + 12 + q];
                float w0 = P.dinv[s0], w1 = P.dinv[s1];
                float w2 = P.dinv[s2], w3 = P.dinv[s3];
                uint4 u0 = xb4[(size_t)s0 * 16 + p];
                uint4 u1 = xb4[(size_t)s1 * 16 + p];
                uint4 u2 = xb4[(size_t)s2 * 16 + p];
                uint4 u3 = xb4[(size_t)s3 * 16 + p];
                acc8(acc, u0, w0);
                acc8(acc, u1, w1);
                acc8(acc, u2, w2);
                acc8(acc, u3, w3);
            }
            for (; e + 4 <= end; e += 4) {
                int s = P.csr[e + q];
                float w = P.dinv[s];
                uint4 u = xb4[(size_t)s * 16 + p];
                acc8(acc, u, w);
            }
            if (e < end) {                     // predicated tail
                int idx = e + q;
                bool valid = idx < end;
                int s = valid ? P.csr[idx] : node;
                float w = valid ? P.dinv[s] : 0.f;
                uint4 u = xb4[(size_t)s * 16 + p];
                acc8(acc, u, w);
            }
#pragma unroll
            for (int j = 0; j < 8; j++) {      // combine quarter partials
                acc[j] += __shfl_xor(acc[j], 16);
                acc[j] += __shfl_xor(acc[j], 32);
            }
            if (q == 0) {                      // finalize + write bf16 row
                const float di = P.dinv[node];
                const float dd = di * di;
                uint4 su = xb4[(size_t)node * 16 + p];
                uint4 o;
                o.x = f2bf(di * acc[0] + dd * bf_lo(su.x)) |
                      (f2bf(di * acc[1] + dd * bf_hi(su.x)) << 16);
                o.y = f2bf(di * acc[2] + dd * bf_lo(su.y)) |
                      (f2bf(di * acc[3] + dd * bf_hi(su.y)) << 16);
                o.z = f2bf(di * acc[4] + dd * bf_lo(su.z)) |
                      (f2bf(di * acc[5] + dd * bf_hi(su.z)) << 16);
                o.w = f2bf(di * acc[6] + dd * bf_lo(su.w)) |
                      (f2bf(di * acc[7] + dd * bf_hi(su.w)) << 16);
                *(uint4*)&A[n][p * 8] = o;
            }
        }
        __syncthreads();

        // MFMA: D[16][512]; wave owns 8 n-tiles of 16 cols
        bf16x8 afr[4];
#pragma unroll
        for (int ks = 0; ks < 4; ks++)
            afr[ks] = *(const bf16x8*)&A[p][ks * 32 + q * 8];

        f32x4 acc[8];
#pragma unroll
        for (int tt = 0; tt < 8; tt++) acc[tt] = (f32x4){0.f, 0.f, 0.f, 0.f};
#pragma unroll
        for (int tt = 0; tt < 8; tt++) {
            const int tile_n = wv * 8 + tt;
#pragma unroll
            for (int ks = 0; ks < 4; ks++) {
                bf16x8 bfr = bpk[(size_t)(tile_n * 4 + ks) * 64 + lane];
                acc[tt] = __builtin_amdgcn_mfma_f32_16x16x32_bf16(afr[ks], bfr, acc[tt], 0, 0, 0);
            }
        }

        // epilogue: zd-partial = relu(D + b1) . W2   (C/D: col=p, row=q*4+r)
        float zp[4] = {0.f, 0.f, 0.f, 0.f};
#pragma unroll
        for (int tt = 0; tt < 8; tt++) {
            const int c = (wv * 8 + tt) * 16 + p;
            const float b1v = P.b1p[c];
            const float w2v = P.w2p[c];
#pragma unroll
            for (int r = 0; r < 4; r++)
                zp[r] += fmaxf(acc[tt][r] + b1v, 0.f) * w2v;
        }
#pragma unroll
        for (int off = 1; off < 16; off <<= 1) {
#pragma unroll
            for (int r = 0; r < 4; r++) zp[r] += __shfl_xor(zp[r], off);
        }
        if (p == 0) {
#pragma unroll
            for (int r = 0; r < 4; r++) red[wv][q * 4 + r] = zp[r];
        }
        __syncthreads();
        if (tid < 16) {
            int node = node0 + tid;
            float zz = red[0][tid] + red[1][tid] + red[2][tid] + red[3][tid];
            P.zd[node] = P.dinv[node] * zz;
        }
    }
    __threadfence();
    grid.sync();

    // ================= P5: layer-2 scalar gather =================
    const float b2v = P.b2[0];
    for (int tile = b; tile < NTILES; tile += gridDim.x) {
        const int node = tile * 16 + (tid >> 4);
        const int l = tid & 15;
        const int start = P.row_ptr[node], end = P.row_ptr[node + 1];
        float s = 0.f;
        for (int e = start + l; e < end; e += 16) s += P.zd[P.csr[e]];
#pragma unroll
        for (int off = 1; off < 16; off <<= 1) s += __shfl_xor(s, off);
        if (l == 0) P.out[node] = P.dinv[node] * (s + P.zd[node]) + b2v;
    }
}

extern "C" void kernel_launch(void* const* d_in, const int* in_sizes, int n_in,
                              void* d_out, int out_size, void* d_ws, size_t ws_size,
                              hipStream_t stream) {
    const float* x  = (const float*)d_in[0];
    const int*   ei = (const int*)d_in[1];     // [2, E]: row 0 = src, row 1 = dst
    const float* W1 = (const float*)d_in[2];
    const float* b1 = (const float*)d_in[3];
    const float* W2 = (const float*)d_in[4];
    const float* b2 = (const float*)d_in[5];

    // Workspace layout (~17.5 MB); everything consumed is (re)written in-kernel.
    uint2* x_bf          = (uint2*)d_ws;                       // 1,600,000 uint2 (12.8 MB)
    unsigned short* b_pk = (unsigned short*)(x_bf + 1600000);  // 65,536 bf16 (128 KB)
    float* b1p    = (float*)(b_pk + 65536);                    // 512
    float* w2p    = b1p + 512;                                 // 512
    float* dinv   = w2p + 512;                                 // 50000
    float* zd     = dinv + N_NODES;                            // 50000
    int* deg      = (int*)(zd + N_NODES);                      // 50000
    unsigned int* state = (unsigned int*)(deg + N_NODES);      // 256
    int* row_ptr  = (int*)(state + 256);                       // 50001
    int* cursor   = row_ptr + N_NODES + 1;                     // 50000
    int* csr      = cursor + N_NODES;                          // 800000

    Params P;
    P.x = x; P.src = ei; P.dst = ei + N_EDGES;
    P.W1 = W1; P.b1 = b1; P.W2 = W2; P.b2 = b2;
    P.out = (float*)d_out;
    P.x_bf = x_bf; P.b_pk = b_pk; P.b1p = b1p; P.w2p = w2p;
    P.dinv = dinv; P.zd = zd; P.deg = deg; P.state = state;
    P.row_ptr = row_ptr; P.cursor = cursor; P.csr = csr;

    int occ = 0;
    hipOccupancyMaxActiveBlocksPerMultiprocessor(&occ, k_all, 256, 0);
    if (occ < 1) occ = 4;                      // conservative fallback
    int grid = occ * 256;                      // 256 CUs on MI355X
    if (grid > 2048) grid = 2048;              // 8 blocks/CU is all we can use
    if (grid < 256) grid = 256;                // scan phase needs >= 196 blocks

    void* args[] = {(void*)&P};
    hipLaunchCooperativeKernel((void*)k_all, dim3(grid), dim3(256), args, 0, stream);
}

// Round 7
// 735.604 us; speedup vs baseline: 1.7374x; 1.7374x over previous
//
#include <hip/hip_runtime.h>
#include <hip/hip_cooperative_groups.h>

namespace cg = cooperative_groups;

// 2-layer GCN in ONE cooperative kernel (5 phases, 4 grid.syncs):
//   (memsetAsync zeroes deg+state before launch)
//   P0: x -> bf16 | W1 -> bf16 B-fragment pack | b1/W2 pad | deg histogram
//   P1: decoupled-lookback exclusive scan -> row_ptr, cursor(seed), dinv  (blocks<196)
//   P2: CSR fill (atomic cursor bump)
//   P3: per 16-node tile: gather A = D^-1/2 (A+I) D^-1/2 X (bf16->LDS),
//       zd = dinv * ( relu(A@W1 + b1) @ W2 ) via mfma_f32_16x16x32_bf16
//   P4: out[i] = dinv[i]*(sum_{s in N(i)} zd[s] + zd[i]) + b2
//
// __launch_bounds__(256,4): the P3 gather/MFMA body compiles to 48 VGPR under
// this budget (R5-measured, no spill). (256,8) caps VGPR at 64 -> 450 MB of
// scratch spill traffic and a 9x regression (R6-measured). Do not raise.

#define N_NODES 50000
#define N_EDGES 800000
#define D_FEAT  128
#define D_HID   500
#define SCANB   196          // ceil(50000/256)
#define NTILES  3125         // 50000 / 16

typedef __bf16 bf16x8 __attribute__((ext_vector_type(8)));
typedef float  f32x4  __attribute__((ext_vector_type(4)));

static __device__ inline unsigned int f2bf(float f) {   // fp32 -> bf16 bits, RTNE
    unsigned int u = __float_as_uint(f);
    return (u + 0x7fffu + ((u >> 16) & 1u)) >> 16;
}
static __device__ inline float bf_lo(unsigned int u) { return __uint_as_float(u << 16); }
static __device__ inline float bf_hi(unsigned int u) { return __uint_as_float(u & 0xffff0000u); }

static __device__ inline void acc8(float* acc, uint4 u, float w) {
    acc[0] = fmaf(w, bf_lo(u.x), acc[0]);
    acc[1] = fmaf(w, bf_hi(u.x), acc[1]);
    acc[2] = fmaf(w, bf_lo(u.y), acc[2]);
    acc[3] = fmaf(w, bf_hi(u.y), acc[3]);
    acc[4] = fmaf(w, bf_lo(u.z), acc[4]);
    acc[5] = fmaf(w, bf_hi(u.z), acc[5]);
    acc[6] = fmaf(w, bf_lo(u.w), acc[6]);
    acc[7] = fmaf(w, bf_hi(u.w), acc[7]);
}

struct Params {
    const float* x;
    const int*   src;
    const int*   dst;
    const float* W1;
    const float* b1;
    const float* W2;
    const float* b2;
    float* out;
    uint2* x_bf;
    unsigned short* b_pk;
    float* b1p;
    float* w2p;
    float* dinv;
    float* zd;
    int* deg;
    unsigned int* state;
    int* row_ptr;
    int* cursor;
    int* csr;
};

__global__ __launch_bounds__(256, 4) void k_all(Params P) {
    cg::grid_group grid = cg::this_grid();
    __shared__ int ps[256];
    __shared__ int s_prefix;
    __shared__ unsigned short A[16][136];   // bf16 rows; 272B stride, 2-way alias = free
    __shared__ float red[4][16];

    const int tid  = threadIdx.x;
    const int b    = blockIdx.x;
    const int gtid = b * 256 + tid;
    const int nthr = gridDim.x * 256;

    // ===== P0: x->bf16 | W1 pack | b1/W2 pad | deg histogram (independent) =====
    for (int i = gtid; i < N_NODES * D_FEAT / 4; i += nthr) {   // x -> bf16, 4/thread
        float4 v = ((const float4*)P.x)[i];
        uint2 o;
        o.x = f2bf(v.x) | (f2bf(v.y) << 16);
        o.y = f2bf(v.z) | (f2bf(v.w) << 16);
        P.x_bf[i] = o;
    }
    for (int idx = gtid; idx < 8192; idx += nthr) {             // W1 B-fragment pack
        int lane = idx & 63;
        int slot = idx >> 6;
        int tt   = slot >> 2;                 // n-tile
        int ks   = slot & 3;                  // k-step
        int quad = lane >> 4;
        int n    = tt * 16 + (lane & 15);
        unsigned int us[8];
#pragma unroll
        for (int j = 0; j < 8; j++) {
            int k = ks * 32 + quad * 8 + j;
            float v = (n < D_HID) ? P.W1[(size_t)k * D_HID + n] : 0.f;
            us[j] = f2bf(v);
        }
        uint4 pk;
        pk.x = us[0] | (us[1] << 16);
        pk.y = us[2] | (us[3] << 16);
        pk.z = us[4] | (us[5] << 16);
        pk.w = us[6] | (us[7] << 16);
        ((uint4*)P.b_pk)[idx] = pk;
    }
    for (int i = gtid; i < 512; i += nthr) {                    // pad b1 / W2
        P.b1p[i] = (i < D_HID) ? P.b1[i] : 0.f;
        P.w2p[i] = (i < D_HID) ? P.W2[i] : 0.f;
    }
    for (int e = gtid; e < N_EDGES; e += nthr)                  // degree histogram
        atomicAdd(&P.deg[P.dst[e]], 1);
    __threadfence();
    grid.sync();

    // ===== P1: decoupled-lookback exclusive scan (blocks < SCANB) =====
    if (b < SCANB) {
        const int i = b * 256 + tid;
        if (tid == 0) s_prefix = 0;
        int v = (i < N_NODES) ? P.deg[i] : 0;
        ps[tid] = v;
        __syncthreads();
        for (int off = 1; off < 256; off <<= 1) {
            int t = (tid >= off) ? ps[tid - off] : 0;
            __syncthreads();
            ps[tid] += t;
            __syncthreads();
        }
        const int total = ps[255];
        if (tid == 0) {
            unsigned int st = (b == 0) ? (0xC0000000u | (unsigned)total)
                                       : (0x40000000u | (unsigned)total);
            __hip_atomic_store(&P.state[b], st, __ATOMIC_RELEASE, __HIP_MEMORY_SCOPE_AGENT);
        }
        if (b > 0 && tid < 64) {               // wave 0: 64-wide lookback
            int prefix = 0;
            int look = b - 1;
            while (true) {
                int idx = look - tid;
                unsigned int st = 0xC0000000u; // idx<0: virtual INCL value 0
                if (idx >= 0)
                    st = __hip_atomic_load(&P.state[idx], __ATOMIC_ACQUIRE,
                                           __HIP_MEMORY_SCOPE_AGENT);
                bool ready = (st >> 30) == 1u || (st >> 30) == 3u;
                if (__ballot(!ready)) continue;
                bool incl = (st >> 30) == 3u;
                unsigned long long im = __ballot(incl);
                int contrib;
                if (im == 0ull) {
                    contrib = (int)(st & 0x3FFFFFFFu);
                } else {
                    int stop = __ffsll(im) - 1;
                    contrib = (tid <= stop) ? (int)(st & 0x3FFFFFFFu) : 0;
                }
#pragma unroll
                for (int off = 32; off >= 1; off >>= 1) contrib += __shfl_xor(contrib, off);
                prefix += contrib;
                if (im != 0ull) break;
                look -= 64;
            }
            if (tid == 0) {
                s_prefix = prefix;
                __hip_atomic_store(&P.state[b], 0xC0000000u | (unsigned)(prefix + total),
                                   __ATOMIC_RELEASE, __HIP_MEMORY_SCOPE_AGENT);
            }
        }
        __syncthreads();
        const int bp = s_prefix;
        if (i < N_NODES) {
            int r = bp + ps[tid] - v;          // exclusive prefix
            P.row_ptr[i] = r;
            P.cursor[i] = r;
            P.dinv[i] = rsqrtf((float)(v + 1));
        }
        if (b == 0 && tid == 0) P.row_ptr[N_NODES] = N_EDGES;
    }
    __threadfence();
    grid.sync();

    // ===== P2: CSR fill =====
    for (int e = gtid; e < N_EDGES; e += nthr) {
        int pos = atomicAdd(&P.cursor[P.dst[e]], 1);
        P.csr[pos] = P.src[e];
    }
    __threadfence();
    grid.sync();

    // ===== P3: fused gather + bf16 MFMA MLP =====
    const int wv = tid >> 6, lane = tid & 63;
    const int q = lane >> 4, p = lane & 15;
    const uint4* __restrict__ xb4 = (const uint4*)P.x_bf;
    const bf16x8* __restrict__ bpk = (const bf16x8*)P.b_pk;

    for (int tile = b; tile < NTILES; tile += gridDim.x) {
        const int node0 = tile * 16;
        // gather: wave handles 4 nodes; quarter-wave q owns edge e+q (16B/lane)
        for (int nn = 0; nn < 4; nn++) {
            const int n = wv * 4 + nn;
            const int node = node0 + n;
            int e = P.row_ptr[node];
            const int end = P.row_ptr[node + 1];
            float acc[8];
#pragma unroll
            for (int j = 0; j < 8; j++) acc[j] = 0.f;

            for (; e + 16 <= end; e += 16) {   // 16 edges / wave iteration
                int s0 = P.csr[e + q];
                int s1 = P.csr[e + 4 + q];
                int s2 = P.csr[e + 8 + q];
                int s3 = P.csr[e + 12 + q];
                float w0 = P.dinv[s0], w1 = P.dinv[s1];
                float w2 = P.dinv[s2], w3 = P.dinv[s3];
                uint4 u0 = xb4[(size_t)s0 * 16 + p];
                uint4 u1 = xb4[(size_t)s1 * 16 + p];
                uint4 u2 = xb4[(size_t)s2 * 16 + p];
                uint4 u3 = xb4[(size_t)s3 * 16 + p];
                acc8(acc, u0, w0);
                acc8(acc, u1, w1);
                acc8(acc, u2, w2);
                acc8(acc, u3, w3);
            }
            for (; e + 4 <= end; e += 4) {
                int s = P.csr[e + q];
                float w = P.dinv[s];
                uint4 u = xb4[(size_t)s * 16 + p];
                acc8(acc, u, w);
            }
            if (e < end) {                     // predicated tail
                int idx = e + q;
                bool valid = idx < end;
                int s = valid ? P.csr[idx] : node;
                float w = valid ? P.dinv[s] : 0.f;
                uint4 u = xb4[(size_t)s * 16 + p];
                acc8(acc, u, w);
            }
#pragma unroll
            for (int j = 0; j < 8; j++) {      // combine quarter partials
                acc[j] += __shfl_xor(acc[j], 16);
                acc[j] += __shfl_xor(acc[j], 32);
            }
            if (q == 0) {                      // finalize + write bf16 row
                const float di = P.dinv[node];
                const float dd = di * di;
                uint4 su = xb4[(size_t)node * 16 + p];
                uint4 o;
                o.x = f2bf(di * acc[0] + dd * bf_lo(su.x)) |
                      (f2bf(di * acc[1] + dd * bf_hi(su.x)) << 16);
                o.y = f2bf(di * acc[2] + dd * bf_lo(su.y)) |
                      (f2bf(di * acc[3] + dd * bf_hi(su.y)) << 16);
                o.z = f2bf(di * acc[4] + dd * bf_lo(su.z)) |
                      (f2bf(di * acc[5] + dd * bf_hi(su.z)) << 16);
                o.w = f2bf(di * acc[6] + dd * bf_lo(su.w)) |
                      (f2bf(di * acc[7] + dd * bf_hi(su.w)) << 16);
                *(uint4*)&A[n][p * 8] = o;
            }
        }
        __syncthreads();

        // MFMA: D[16][512]; wave owns 8 n-tiles of 16 cols
        bf16x8 afr[4];
#pragma unroll
        for (int ks = 0; ks < 4; ks++)
            afr[ks] = *(const bf16x8*)&A[p][ks * 32 + q * 8];

        f32x4 acc[8];
#pragma unroll
        for (int tt = 0; tt < 8; tt++) acc[tt] = (f32x4){0.f, 0.f, 0.f, 0.f};
#pragma unroll
        for (int tt = 0; tt < 8; tt++) {
            const int tile_n = wv * 8 + tt;
#pragma unroll
            for (int ks = 0; ks < 4; ks++) {
                bf16x8 bfr = bpk[(size_t)(tile_n * 4 + ks) * 64 + lane];
                acc[tt] = __builtin_amdgcn_mfma_f32_16x16x32_bf16(afr[ks], bfr, acc[tt], 0, 0, 0);
            }
        }

        // epilogue: zd-partial = relu(D + b1) . W2   (C/D: col=p, row=q*4+r)
        float zp[4] = {0.f, 0.f, 0.f, 0.f};
#pragma unroll
        for (int tt = 0; tt < 8; tt++) {
            const int c = (wv * 8 + tt) * 16 + p;
            const float b1v = P.b1p[c];
            const float w2v = P.w2p[c];
#pragma unroll
            for (int r = 0; r < 4; r++)
                zp[r] += fmaxf(acc[tt][r] + b1v, 0.f) * w2v;
        }
#pragma unroll
        for (int off = 1; off < 16; off <<= 1) {
#pragma unroll
            for (int r = 0; r < 4; r++) zp[r] += __shfl_xor(zp[r], off);
        }
        if (p == 0) {
#pragma unroll
            for (int r = 0; r < 4; r++) red[wv][q * 4 + r] = zp[r];
        }
        __syncthreads();
        if (tid < 16) {
            int node = node0 + tid;
            float zz = red[0][tid] + red[1][tid] + red[2][tid] + red[3][tid];
            P.zd[node] = P.dinv[node] * zz;
        }
        __syncthreads();                       // A/red reused next tile iteration
    }
    __threadfence();
    grid.sync();

    // ===== P4: layer-2 scalar gather =====
    const float b2v = P.b2[0];
    for (int tile = b; tile < NTILES; tile += gridDim.x) {
        const int node = tile * 16 + (tid >> 4);
        const int l = tid & 15;
        const int start = P.row_ptr[node], end = P.row_ptr[node + 1];
        float s = 0.f;
        for (int e = start + l; e < end; e += 16) s += P.zd[P.csr[e]];
#pragma unroll
        for (int off = 1; off < 16; off <<= 1) s += __shfl_xor(s, off);
        if (l == 0) P.out[node] = P.dinv[node] * (s + P.zd[node]) + b2v;
    }
}

extern "C" void kernel_launch(void* const* d_in, const int* in_sizes, int n_in,
                              void* d_out, int out_size, void* d_ws, size_t ws_size,
                              hipStream_t stream) {
    const float* x  = (const float*)d_in[0];
    const int*   ei = (const int*)d_in[1];     // [2, E]: row 0 = src, row 1 = dst
    const float* W1 = (const float*)d_in[2];
    const float* b1 = (const float*)d_in[3];
    const float* W2 = (const float*)d_in[4];
    const float* b2 = (const float*)d_in[5];

    // Workspace layout (~17.5 MB). deg and state adjacent -> one memset.
    uint2* x_bf          = (uint2*)d_ws;                       // 1,600,000 uint2 (12.8 MB)
    unsigned short* b_pk = (unsigned short*)(x_bf + 1600000);  // 65,536 bf16 (128 KB)
    float* b1p    = (float*)(b_pk + 65536);                    // 512
    float* w2p    = b1p + 512;                                 // 512
    float* dinv   = w2p + 512;                                 // 50000
    float* zd     = dinv + N_NODES;                            // 50000
    int* deg      = (int*)(zd + N_NODES);                      // 50000
    unsigned int* state = (unsigned int*)(deg + N_NODES);      // 256
    int* row_ptr  = (int*)(state + 256);                       // 50001
    int* cursor   = row_ptr + N_NODES + 1;                     // 50000
    int* csr      = cursor + N_NODES;                          // 800000

    Params P;
    P.x = x; P.src = ei; P.dst = ei + N_EDGES;
    P.W1 = W1; P.b1 = b1; P.W2 = W2; P.b2 = b2;
    P.out = (float*)d_out;
    P.x_bf = x_bf; P.b_pk = b_pk; P.b1p = b1p; P.w2p = w2p;
    P.dinv = dinv; P.zd = zd; P.deg = deg; P.state = state;
    P.row_ptr = row_ptr; P.cursor = cursor; P.csr = csr;

    hipMemsetAsync(deg, 0, (N_NODES + 256) * sizeof(int), stream);

    int occ = 0;
    hipOccupancyMaxActiveBlocksPerMultiprocessor(&occ, k_all, 256, 0);
    if (occ < 1) occ = 1;
    int grid = occ * 256;                      // 256 CUs on MI355X
    if (grid > 2048) grid = 2048;
    if (grid < 256) grid = 256;                // scan phase needs >= 196 blocks

    void* args[] = {(void*)&P};
    hipLaunchCooperativeKernel((void*)k_all, dim3(grid), dim3(256), args, 0, stream);
}